// Round 5
// baseline (2848.806 us; speedup 1.0000x reference)
//
#include <hip/hip_runtime.h>

// ---------------------------------------------------------------------------
// RNN_Layer: x[B,T,C] fp32 -> conv1x1(w_in) -> dense(kernel) -> LSTM(rec)
//            -> dense(w_out).  B=32 T=1024 C=512 D=256 U=256 O=256.
// R11: dual-pipe LSTM (R9 design, de-risked).  Single-pipe floors measured:
// MFMA M=1 GEMV = 26 MAC/cyc/SIMD (R7: 1775us), VALU f16-dot = 32 (R6/R8:
// ~2x floor due to AGPR shuffle when arch-VGPR budget was 128).  Dual-pipe:
// per SIMD, MFMA wave (64 mfma = 1242cyc) || VALU wave (256 fdot2 ~1024cyc)
// -> ~1.3-1.6k cyc/step.  Arch-VGPR cap is 256/wave (R10: hard max), so:
//   MFMA waves 0-3: 6 strips resident (192 reg, MFMA can pull from AGPR),
//     2 strips streamed from LDS.  A = h broadcast to all 16 rows (R10-
//     verified): every lane reads the same h-frag -> all D rows equal z.
//   pk waves 4-7: thread owns unit c; cols 512+c (g), 768+c (o); per col
//     128 f16 k-pairs: 96 resident (2x96=192 reg), 32 streamed from LDS.
//     fdot2 (fp32 acc, R6-verified).  h pairs read as uniform uint4 (bcast).
//   Gates fused in pk thread c: (z_i,z_f) arrive via zsh float2; 2 lgkm-only
//   barriers/step.  __launch_bounds__(512,2) -> 256-reg budget (attribute
//   form gave 124 in R6/R8).
// ---------------------------------------------------------------------------

#define DEV static __device__ __forceinline__

typedef __attribute__((ext_vector_type(8))) short short8;
typedef __attribute__((ext_vector_type(4))) float floatx4;
typedef _Float16 half2v __attribute__((ext_vector_type(2)));
typedef _Float16 half8 __attribute__((ext_vector_type(8)));

static constexpr int Bsz = 32, T = 1024, C = 512, D = 256, U = 256, FU = 1024;
static constexpr int M = Bsz * T;   // 32768 rows for all GEMMs

DEV float bfu2f(unsigned int u) { union { unsigned int i; float f; } v; v.i = u; return v.f; }
DEV float bf2f(unsigned short u) { return bfu2f(((unsigned int)u) << 16); }
DEV unsigned short f2bf(float f) {
    union { float f; unsigned int i; } v; v.f = f;
    return (unsigned short)((v.i + 0x7fffu + ((v.i >> 16) & 1u)) >> 16);
}
DEV float sigmf(float x) { return 1.0f / (1.0f + __expf(-x)); }
DEV float tanhfast(float x) {
    const float a = __expf(-2.0f * fabsf(x));
    const float t = (1.0f - a) / (1.0f + a);
    return copysignf(t, x);
}
DEV half8 h8c(uint4 v) { return __builtin_bit_cast(half8, v); }

// 2-way f16 dot with fp32 accumulate: z += w.lo*a.lo + w.hi*a.hi (R6-verified)
DEV float dot2h(unsigned int w, unsigned int a, float acc) {
#if __has_builtin(__builtin_amdgcn_fdot2)
    return __builtin_amdgcn_fdot2(__builtin_bit_cast(half2v, w),
                                  __builtin_bit_cast(half2v, a), acc, false);
#else
    const half2v wv = __builtin_bit_cast(half2v, w);
    const half2v av = __builtin_bit_cast(half2v, a);
    return acc + (float)wv[0] * (float)av[0] + (float)wv[1] * (float)av[1];
#endif
}

// fp32-or-bf16 element -> bf16 bit pattern (GEMM operand loads)
DEV short ld_bf(const float* p) { return (short)f2bf(*p); }
DEV short ld_bf(const unsigned short* p) { return (short)*p; }
DEV short8 ld_frag(const unsigned short* p) { return *(const short8*)p; }
DEV short8 ld_frag(const float* p) {
    short8 v;
#pragma unroll
    for (int j = 0; j < 8; j++) v[j] = (short)f2bf(p[j]);
    return v;
}
DEV float ldxz1(const float* p) { return *p; }
DEV float ldxz1(const unsigned short* p) { return bf2f(*p); }

// lgkm-only barrier: cross-thread data is LDS-only; skip the vmcnt(0) drain
// (xz prefetch loads / hs stores are thread-local and stay in flight).
#define BAR() asm volatile("s_waitcnt lgkmcnt(0)\n\ts_barrier" ::: "memory")

// ---------------------------------------------------------------------------
// Fragment-direct MFMA GEMM:  C[M,N] = A[M,K] @ B[K,N] + bias[N]
// Layouts (m89/m120-verified): A[m=lane&15][k=quad*8+j];
//   B[k=quad*8+j][n=lane&15]; D[m=quad*4+r][n=lane&15]
// ---------------------------------------------------------------------------
template <int K, int N, int MT, int NS, bool OUTF32, typename AT, typename BT>
__global__ __launch_bounds__(64) void gemm_mfma(
    const AT* __restrict__ A,
    const BT* __restrict__ Bm,
    const float* __restrict__ bias,
    void* __restrict__ Cv)
{
    constexpr int KC = K / 32;
    const int lane = threadIdx.x;
    const int quad = lane >> 4, lr = lane & 15;
    constexpr int NSG = N / (16 * NS);
    const int sg = blockIdx.x % NSG;
    const int mb = blockIdx.x / NSG;
    const int n0 = sg * 16 * NS;

    short8 bf[NS][KC];
    float biasv[NS];
#pragma unroll
    for (int s = 0; s < NS; s++) {
        const int n = n0 + s * 16 + lr;
        biasv[s] = bias[n];
#pragma unroll
        for (int kc = 0; kc < KC; kc++) {
            short8 v;
#pragma unroll
            for (int j = 0; j < 8; j++) {
                const int k = kc * 32 + quad * 8 + j;
                v[j] = ld_bf(&Bm[(size_t)k * N + n]);
            }
            bf[s][kc] = v;
        }
    }

    for (int mt = 0; mt < MT; mt++) {
        const int m0 = (mb * MT + mt) * 16;
        const AT* Ap = A + (size_t)(m0 + lr) * K + quad * 8;
        floatx4 acc[NS];
#pragma unroll
        for (int s = 0; s < NS; s++) acc[s] = (floatx4){0.f, 0.f, 0.f, 0.f};
#pragma unroll
        for (int kc = 0; kc < KC; kc++) {
            short8 af = ld_frag(Ap + kc * 32);
#pragma unroll
            for (int s = 0; s < NS; s++)
                acc[s] = __builtin_amdgcn_mfma_f32_16x16x32_bf16(af, bf[s][kc], acc[s], 0, 0, 0);
        }
#pragma unroll
        for (int s = 0; s < NS; s++) {
            const int n = n0 + s * 16 + lr;
#pragma unroll
            for (int r = 0; r < 4; r++) {
                const int m = m0 + quad * 4 + r;
                const float val = acc[s][r] + biasv[s];
                if (OUTF32)
                    ((float*)Cv)[(size_t)m * N + n] = val;
                else
                    ((unsigned short*)Cv)[(size_t)m * N + n] = f2bf(val);
            }
        }
    }
}

// ---------------------------------------------------------------------------
// Pack rec_kernel fp32 [256][1024] -> f16 MFMA B-fragments, strips 0..31
// (cols 0..511 = i,f gates).  Pm[(strip*8+kc)*64+lane].j =
//   f16( rec[kc*32+(lane>>4)*8+j][strip*16+(lane&15)] )   (R7-verified)
// ---------------------------------------------------------------------------
__global__ __launch_bounds__(256) void pack_rec_mfma(const float* __restrict__ rec,
                                                     uint4* __restrict__ Pm)
{
    const int idx = blockIdx.x * 256 + threadIdx.x;   // 0..16383 (32 strips)
    const int lane = idx & 63;
    const int kc = (idx >> 6) & 7;
    const int strip = idx >> 9;
    const int q = lane >> 4, lr = lane & 15;
    const int col = strip * 16 + lr;
    const int k0 = kc * 32 + q * 8;
    union { unsigned short u[8]; uint4 v; } out;
#pragma unroll
    for (int j = 0; j < 8; j++) {
        const _Float16 h = (_Float16)rec[(size_t)(k0 + j) * FU + col];
        out.u[j] = __builtin_bit_cast(unsigned short, h);
    }
    Pm[idx] = out.v;
}

// ---------------------------------------------------------------------------
// Pack rec for pk role: per k-pair kk (h rows 2kk,2kk+1), unit c in [0,256):
//   val_g = pack_f16(W[2kk][512+c], W[2kk+1][512+c])   (g-gate col)
//   val_o = pack_f16(W[2kk][768+c], W[2kk+1][768+c])   (o-gate col)
// kk<96 -> resident: Pg_res/Po_res[kk*256+c]
// kk>=96 -> streamed uint4 rows: row j=(kk-96)>>2, elem (kk-96)&3
// ---------------------------------------------------------------------------
__global__ __launch_bounds__(256) void pack_rec_pk3(const float* __restrict__ rec,
                                                    unsigned int* __restrict__ Pg_res,
                                                    unsigned int* __restrict__ Po_res,
                                                    unsigned int* __restrict__ Pg_st,
                                                    unsigned int* __restrict__ Po_st)
{
    const int idx = blockIdx.x * 256 + threadIdx.x;   // 0..32767
    const int kk = idx >> 8, c = idx & 255;
    const _Float16 g_lo = (_Float16)rec[(size_t)(2 * kk) * FU + 512 + c];
    const _Float16 g_hi = (_Float16)rec[(size_t)(2 * kk + 1) * FU + 512 + c];
    const _Float16 o_lo = (_Float16)rec[(size_t)(2 * kk) * FU + 768 + c];
    const _Float16 o_hi = (_Float16)rec[(size_t)(2 * kk + 1) * FU + 768 + c];
    const unsigned int vg = (unsigned int)__builtin_bit_cast(unsigned short, g_lo)
                          | ((unsigned int)__builtin_bit_cast(unsigned short, g_hi) << 16);
    const unsigned int vo = (unsigned int)__builtin_bit_cast(unsigned short, o_lo)
                          | ((unsigned int)__builtin_bit_cast(unsigned short, o_hi) << 16);
    if (kk < 96) {
        Pg_res[(size_t)kk * 256 + c] = vg;
        Po_res[(size_t)kk * 256 + c] = vo;
    } else {
        const int j = kk - 96;
        Pg_st[((size_t)(j >> 2) * 256 + c) * 4 + (j & 3)] = vg;
        Po_st[((size_t)(j >> 2) * 256 + c) * 4 + (j & 3)] = vo;
    }
}

// ---------------------------------------------------------------------------
// Dual-pipe LSTM. 1 WG (512 thr / 8 waves, 2 waves/SIMD, 256-reg budget) per
// batch.  Waves 0-3: MFMA role (z_i, z_f).  Waves 4-7: fdot2 role (z_g, z_o)
// + gates.  One h buffer: read in compute phase, written between BAR1/BAR2.
// ---------------------------------------------------------------------------
template <typename XZT>
__global__ __launch_bounds__(512, 2)
void lstm_dual(
    const XZT* __restrict__ xz,            // [B, T, 4U]
    const uint4* __restrict__ Pm,          // mfma B-frags, strips 0..31
    const unsigned int* __restrict__ Pg_res,   // [96][256]
    const unsigned int* __restrict__ Po_res,   // [96][256]
    const uint4* __restrict__ Pg_st,       // [8][256] uint4
    const uint4* __restrict__ Po_st,       // [8][256] uint4
    unsigned short* __restrict__ hs)       // [B, T, U] bf16 out
{
    const int b = blockIdx.x;
    const int tid = threadIdx.x;
    const int w = tid >> 6;                // wave 0..7
    const int lane = tid & 63;
    const int q = lane >> 4, lr = lane & 15;

    __shared__ uint4 Wl[8 * 8 * 64];       // mfma streamed f-strips: 64 KiB
    __shared__ uint4 Pgs[8 * 256];         // pk streamed g kpairs: 32 KiB
    __shared__ uint4 Pos[8 * 256];         // pk streamed o kpairs: 32 KiB
    __shared__ float2 zsh[U];              // (z_i, z_f) per unit: 2 KiB
    __shared__ __align__(16) unsigned short h_pk[U];   // h f16: 512 B

    // ---- one-time staging ----
    // Wl slot sl (0..7): wave sl>>1, idx sl&1 -> global strip 18+4*(sl>>1)+(sl&1)
    for (int i = tid; i < 8 * 8 * 64; i += 512) {
        const int sl = i >> 9;
        const int gs = 18 + 4 * (sl >> 1) + (sl & 1);
        Wl[i] = Pm[(size_t)gs * 512 + (i & 511)];
    }
    for (int i = tid; i < 8 * 256; i += 512) { Pgs[i] = Pg_st[i]; Pos[i] = Po_st[i]; }
    if (tid < 128) ((unsigned int*)h_pk)[tid] = 0;
    __syncthreads();

    const XZT* xzb = xz + (size_t)b * T * FU;
    unsigned short* hsb = hs + (size_t)b * T * U;

    if (w < 4) {
        // =============== MFMA role: z_i, z_f for units 64w..64w+63 =========
        // resident: i strips 4w..4w+3, f strips 16+4w, 17+4w (192 regs;
        // feed MFMA only -> allocator may use AGPRs, read natively by MFMA)
        uint4 Wr[6][8];
#pragma unroll
        for (int s = 0; s < 6; s++) {
            const int strip = (s < 4) ? (4 * w + s) : (16 + 4 * w + (s - 4));
#pragma unroll
            for (int kc = 0; kc < 8; kc++)
                Wr[s][kc] = Pm[((size_t)strip * 8 + kc) * 64 + lane];
        }
#pragma unroll
        for (int s = 0; s < 6; s++)
#pragma unroll
            for (int kc = 0; kc < 8; kc++)
                asm volatile("" : "+v"(Wr[s][kc].x), "+v"(Wr[s][kc].y),
                                 "+v"(Wr[s][kc].z), "+v"(Wr[s][kc].w));

        const char* hp = (const char*)h_pk;
        for (int t = 0; t < T; t++) {
            floatx4 acc[8];
#pragma unroll
            for (int s = 0; s < 8; s++) acc[s] = (floatx4){0.f, 0.f, 0.f, 0.f};
#pragma unroll
            for (int kc = 0; kc < 8; kc++) {
                // A-frag: 4-way broadcast b128 of h[kc*32+q*8..+7]; all 16
                // A-rows equal h -> all D rows equal z (R10-verified).
                const uint4 af = *(const uint4*)(hp + kc * 64 + q * 16);
                const uint4 s6 = Wl[((w * 2 + 0) * 8 + kc) * 64 + lane];
                const uint4 s7 = Wl[((w * 2 + 1) * 8 + kc) * 64 + lane];
                acc[0] = __builtin_amdgcn_mfma_f32_16x16x32_f16(h8c(af), h8c(Wr[0][kc]), acc[0], 0, 0, 0);
                acc[1] = __builtin_amdgcn_mfma_f32_16x16x32_f16(h8c(af), h8c(Wr[1][kc]), acc[1], 0, 0, 0);
                acc[2] = __builtin_amdgcn_mfma_f32_16x16x32_f16(h8c(af), h8c(Wr[2][kc]), acc[2], 0, 0, 0);
                acc[3] = __builtin_amdgcn_mfma_f32_16x16x32_f16(h8c(af), h8c(Wr[3][kc]), acc[3], 0, 0, 0);
                acc[4] = __builtin_amdgcn_mfma_f32_16x16x32_f16(h8c(af), h8c(Wr[4][kc]), acc[4], 0, 0, 0);
                acc[5] = __builtin_amdgcn_mfma_f32_16x16x32_f16(h8c(af), h8c(Wr[5][kc]), acc[5], 0, 0, 0);
                acc[6] = __builtin_amdgcn_mfma_f32_16x16x32_f16(h8c(af), h8c(s6), acc[6], 0, 0, 0);
                acc[7] = __builtin_amdgcn_mfma_f32_16x16x32_f16(h8c(af), h8c(s7), acc[7], 0, 0, 0);
            }
            // D row 0 lives in q==0 lanes, elem 0; col = lr.
            // acc[s] (s<4): i-gate, unit 64w+16s+lr; acc[4..7]: f-gate, same units.
            if (q == 0) {
#pragma unroll
                for (int s = 0; s < 4; s++)
                    zsh[64 * w + 16 * s + lr] = make_float2(acc[s][0], acc[s + 4][0]);
            }
            BAR();   // z_if published
            BAR();   // h published (by pk waves)
        }
    } else {
        // =============== pk role: z_g, z_o + gates for unit c ==============
        const int c = tid - 256;           // unit 0..255
        unsigned int Wg[96], Wo[96];
#pragma unroll
        for (int i = 0; i < 96; i++) Wg[i] = Pg_res[(size_t)i * 256 + c];
#pragma unroll
        for (int i = 0; i < 96; i++) Wo[i] = Po_res[(size_t)i * 256 + c];
#pragma unroll
        for (int i = 0; i < 96; i++) asm volatile("" : "+v"(Wg[i]), "+v"(Wo[i]));

        float cst = 0.f;
        float xzi = ldxz1(xzb + c),       xzf = ldxz1(xzb + 256 + c);
        float xzg = ldxz1(xzb + 512 + c), xzo = ldxz1(xzb + 768 + c);

        for (int t = 0; t < T; t++) {
            float xzi_n = 0.f, xzf_n = 0.f, xzg_n = 0.f, xzo_n = 0.f;
            if (t + 1 < T) {
                const XZT* xt = xzb + (size_t)(t + 1) * FU;
                xzi_n = ldxz1(xt + c);       xzf_n = ldxz1(xt + 256 + c);
                xzg_n = ldxz1(xt + 512 + c); xzo_n = ldxz1(xt + 768 + c);
            }

            const uint4* HQ = (const uint4*)h_pk;  // HQ[qb] = kpairs 4qb..4qb+3
            float zg = xzg, zo = xzo;
#pragma unroll
            for (int qb = 0; qb < 24; qb++) {
                const uint4 hw = HQ[qb];
                zg = dot2h(Wg[4 * qb + 0], hw.x, zg); zo = dot2h(Wo[4 * qb + 0], hw.x, zo);
                zg = dot2h(Wg[4 * qb + 1], hw.y, zg); zo = dot2h(Wo[4 * qb + 1], hw.y, zo);
                zg = dot2h(Wg[4 * qb + 2], hw.z, zg); zo = dot2h(Wo[4 * qb + 2], hw.z, zo);
                zg = dot2h(Wg[4 * qb + 3], hw.w, zg); zo = dot2h(Wo[4 * qb + 3], hw.w, zo);
            }
#pragma unroll
            for (int qb = 24; qb < 32; qb++) {
                const uint4 hw = HQ[qb];
                const uint4 wg = Pgs[(qb - 24) * 256 + c];
                const uint4 wo = Pos[(qb - 24) * 256 + c];
                zg = dot2h(wg.x, hw.x, zg); zo = dot2h(wo.x, hw.x, zo);
                zg = dot2h(wg.y, hw.y, zg); zo = dot2h(wo.y, hw.y, zo);
                zg = dot2h(wg.z, hw.z, zg); zo = dot2h(wo.z, hw.z, zo);
                zg = dot2h(wg.w, hw.w, zg); zo = dot2h(wo.w, hw.w, zo);
            }

            BAR();   // z_if ready (and our h reads are done)
            const float2 zif = zsh[c];
            const float iv = sigmf(zif.x + xzi);
            const float fv = sigmf(zif.y + xzf);
            const float gv = tanhfast(zg);
            const float ov = sigmf(zo);
            cst = fv * cst + iv * gv;
            const float hv = ov * tanhfast(cst);
            h_pk[c] = __builtin_bit_cast(unsigned short, (_Float16)hv);
            hsb[(size_t)t * U + c] = f2bf(hv);
            BAR();   // h published

            xzi = xzi_n; xzf = xzf_n; xzg = xzg_n; xzo = xzo_n;
        }
    }
}

// ---------------------------------------------------------------------------
extern "C" void kernel_launch(void* const* d_in, const int* in_sizes, int n_in,
                              void* d_out, int out_size, void* d_ws, size_t ws_size,
                              hipStream_t stream)
{
    const float* x    = (const float*)d_in[0];
    const float* w_in = (const float*)d_in[1];
    const float* b_in = (const float*)d_in[2];
    const float* kern = (const float*)d_in[3];
    const float* rec  = (const float*)d_in[4];
    const float* bias = (const float*)d_in[5];
    const float* wout = (const float*)d_in[6];
    const float* bout = (const float*)d_in[7];

    char* ws = (char*)d_ws;
    const size_t pm_bytes  = (size_t)32 * 8 * 64 * 16;   // 256 KiB (strips 0..31)
    const size_t pgr_bytes = (size_t)96 * 256 * 4;       // 96 KiB
    const size_t pgs_bytes = (size_t)8 * 256 * 16;       // 32 KiB
    const size_t rec_bytes = pm_bytes + 2 * pgr_bytes + 2 * pgs_bytes;  // 512 KiB
    const size_t xin_bytes = (size_t)M * D * 2;          // 16 MiB
    const size_t hs_bytes  = (size_t)M * U * 2;          // 16 MiB
    const size_t xz32_bytes = (size_t)M * FU * 4;        // 128 MiB
    const size_t base = rec_bytes + xin_bytes + hs_bytes;

    uint4* Pm = (uint4*)ws;
    unsigned int* Pg_res = (unsigned int*)(ws + pm_bytes);
    unsigned int* Po_res = (unsigned int*)(ws + pm_bytes + pgr_bytes);
    unsigned int* Pg_st  = (unsigned int*)(ws + pm_bytes + 2 * pgr_bytes);
    unsigned int* Po_st  = (unsigned int*)(ws + pm_bytes + 2 * pgr_bytes + pgs_bytes);
    unsigned short* xin_bf = (unsigned short*)(ws + rec_bytes);
    unsigned short* hs_bf  = (unsigned short*)(ws + rec_bytes + xin_bytes);
    char* xz_raw = ws + base;

    const bool use_f32 = ws_size >= base + xz32_bytes;

    // pack rec_kernel (every launch; ws re-poisoned)
    pack_rec_mfma<<<64, 256, 0, stream>>>(rec, Pm);
    pack_rec_pk3<<<128, 256, 0, stream>>>(rec, Pg_res, Po_res, Pg_st, Po_st);

    // GEMM1: xin = bf16(x @ w_in + b_in)   [M,512]x[512,256]
    gemm_mfma<512, 256, 16, 2, false><<<(256 / 32) * (M / 256), 64, 0, stream>>>(
        x, w_in, b_in, (void*)xin_bf);

    if (use_f32) {
        float* xzp = (float*)xz_raw;
        gemm_mfma<256, 1024, 16, 2, true><<<(1024 / 32) * (M / 256), 64, 0, stream>>>(
            xin_bf, kern, bias, (void*)xzp);
        lstm_dual<float><<<Bsz, 512, 0, stream>>>(
            xzp, Pm, Pg_res, Po_res, (const uint4*)Pg_st, (const uint4*)Po_st, hs_bf);
    } else {
        unsigned short* xzp = (unsigned short*)xz_raw;
        gemm_mfma<256, 1024, 16, 2, false><<<(1024 / 32) * (M / 256), 64, 0, stream>>>(
            xin_bf, kern, bias, (void*)xzp);
        lstm_dual<unsigned short><<<Bsz, 512, 0, stream>>>(
            xzp, Pm, Pg_res, Po_res, (const uint4*)Pg_st, (const uint4*)Po_st, hs_bf);
    }

    // GEMM3: out = fp32(hs @ w_out + b_out)  [M,256]x[256,256]
    gemm_mfma<256, 256, 16, 2, true><<<(256 / 32) * (M / 256), 64, 0, stream>>>(
        hs_bf, wout, bout, d_out);
}